// Round 3
// baseline (1156.469 us; speedup 1.0000x reference)
//
#include <hip/hip_runtime.h>

#define N_NODES 100000
#define N_EDGES 1600000
#define EMBED_DIM 64

#define RPB 64                                   // rows per bucket
#define NBKT ((N_NODES + RPB - 1) / RPB)         // 1563
#define SCAN_ITEMS ((NBKT + 255) / 256)          // 7

// ---------- pass 1: histogram of buckets ----------
__global__ __launch_bounds__(256) void k_hist(const int* __restrict__ rows,
                                              int* __restrict__ cnt) {
    int e = blockIdx.x * 256 + threadIdx.x;
    if (e < N_EDGES) atomicAdd(&cnt[rows[e] >> 6], 1);
}

// ---------- pass 2: single-block exclusive scan over 1563 buckets ----------
__global__ __launch_bounds__(256) void k_scan(const int* __restrict__ cnt,
                                              int* __restrict__ bkt_ptr,
                                              int* __restrict__ cursor) {
    __shared__ int s[256];
    int tid = threadIdx.x;
    int base = tid * SCAN_ITEMS;
    int v[SCAN_ITEMS];
    int t = 0;
#pragma unroll
    for (int i = 0; i < SCAN_ITEMS; ++i) {
        int idx = base + i;
        v[i] = (idx < NBKT) ? cnt[idx] : 0;
        t += v[i];
    }
    s[tid] = t;
    __syncthreads();
    for (int off = 1; off < 256; off <<= 1) {
        int a = s[tid];
        int add = (tid >= off) ? s[tid - off] : 0;
        __syncthreads();
        s[tid] = a + add;
        __syncthreads();
    }
    int run = (tid == 0) ? 0 : s[tid - 1];
#pragma unroll
    for (int i = 0; i < SCAN_ITEMS; ++i) {
        int idx = base + i;
        if (idx < NBKT) {
            bkt_ptr[idx] = run;
            cursor[idx] = run;
        }
        run += v[i];
    }
    if (tid == 255) bkt_ptr[NBKT] = run;  // == N_EDGES
}

// ---------- pass 3: scatter packed (lrow|col, val) into bucket regions ----------
__global__ __launch_bounds__(256) void k_scatter_bkt(const int* __restrict__ rows,
                                                     const int* __restrict__ cols,
                                                     const float* __restrict__ vals,
                                                     int* __restrict__ cursor,
                                                     int2* __restrict__ packed) {
    int e = blockIdx.x * 256 + threadIdx.x;
    if (e >= N_EDGES) return;
    int r = rows[e];
    int b = r >> 6;
    int lrow = r & (RPB - 1);
    int p = atomicAdd(&cursor[b], 1);
    packed[p] = make_int2((lrow << 17) | cols[e], __float_as_int(vals[e]));
}

// ---------- pass 4: one block per bucket, LDS accumulate, dense write ----------
__global__ __launch_bounds__(256) void k_accum(const float* __restrict__ x,
                                               const int* __restrict__ bkt_ptr,
                                               const int2* __restrict__ packed,
                                               float* __restrict__ out) {
    __shared__ float acc[RPB * EMBED_DIM];  // 16 KB
    int tid = threadIdx.x;
    for (int i = tid; i < RPB * EMBED_DIM; i += 256) acc[i] = 0.f;
    __syncthreads();

    int b = blockIdx.x;
    int beg = bkt_ptr[b];
    int end = bkt_ptr[b + 1];
    int w = tid >> 6;        // wave in block (0..3)
    int lane = tid & 63;     // embedding dim

    int e = beg + w;
    // 2-edge unroll for ILP on the gather loads
    for (; e + 4 < end; e += 8) {
        int2 p0 = packed[e];
        int2 p1 = packed[e + 4];
        int c0 = p0.x & 0x1FFFF, r0 = p0.x >> 17;
        int c1 = p1.x & 0x1FFFF, r1 = p1.x >> 17;
        float v0 = __int_as_float(p0.y);
        float v1 = __int_as_float(p1.y);
        float x0 = x[c0 * EMBED_DIM + lane];
        float x1 = x[c1 * EMBED_DIM + lane];
        atomicAdd(&acc[r0 * EMBED_DIM + lane], v0 * x0);
        atomicAdd(&acc[r1 * EMBED_DIM + lane], v1 * x1);
    }
    if (e < end) {
        int2 p = packed[e];
        int c = p.x & 0x1FFFF, r = p.x >> 17;
        float v = __int_as_float(p.y);
        atomicAdd(&acc[r * EMBED_DIM + lane], v * x[c * EMBED_DIM + lane]);
    }
    __syncthreads();

    // dense output: 64 rows x 64 dims = 4096 floats = 1024 float4
    const int vbase = b * (RPB * EMBED_DIM / 4);
    const int vtotal = N_NODES * EMBED_DIM / 4;
    for (int i = tid; i < RPB * EMBED_DIM / 4; i += 256) {
        int gi = vbase + i;
        if (gi < vtotal) {
            ((float4*)out)[gi] = ((const float4*)acc)[i];
        }
    }
}

// ---------- fallback (ws too small): atomic scatter ----------
__global__ __launch_bounds__(256) void spmm_scatter_kernel(
    const float* __restrict__ x, const float* __restrict__ vals,
    const int* __restrict__ rows, const int* __restrict__ cols,
    float* __restrict__ out) {
    const int wave_in_block = threadIdx.x >> 6;
    const int lane = threadIdx.x & 63;
    const int e = blockIdx.x * 4 + wave_in_block;
    if (e >= N_EDGES) return;
    const float m = vals[e] * x[cols[e] * EMBED_DIM + lane];
    atomicAdd(&out[rows[e] * EMBED_DIM + lane], m);
}

extern "C" void kernel_launch(void* const* d_in, const int* in_sizes, int n_in,
                              void* d_out, int out_size, void* d_ws, size_t ws_size,
                              hipStream_t stream) {
    const float* x    = (const float*)d_in[0];
    const float* vals = (const float*)d_in[1];
    const int*   rows = (const int*)d_in[2];
    const int*   cols = (const int*)d_in[3];
    float* out = (float*)d_out;

    // Workspace (ints): bkt_ptr NBKT+1 | cnt NBKT | cursor NBKT | packed 2*E
    const size_t need = ((size_t)(3 * NBKT + 1) + 2 * (size_t)N_EDGES) * 4;
    if (ws_size < need) {
        hipMemsetAsync(out, 0, (size_t)out_size * sizeof(float), stream);
        spmm_scatter_kernel<<<(N_EDGES + 3) / 4, 256, 0, stream>>>(x, vals, rows, cols, out);
        return;
    }

    int* bkt_ptr = (int*)d_ws;
    int* cnt     = bkt_ptr + (NBKT + 1);
    int* cursor  = cnt + NBKT;
    int2* packed = (int2*)(cursor + NBKT);  // offset (3*NBKT+1)*4 B, 8B-aligned

    hipMemsetAsync(cnt, 0, (size_t)NBKT * sizeof(int), stream);

    k_hist<<<(N_EDGES + 255) / 256, 256, 0, stream>>>(rows, cnt);
    k_scan<<<1, 256, 0, stream>>>(cnt, bkt_ptr, cursor);
    k_scatter_bkt<<<(N_EDGES + 255) / 256, 256, 0, stream>>>(rows, cols, vals, cursor, packed);
    k_accum<<<NBKT, 256, 0, stream>>>(x, bkt_ptr, packed, out);
}

// Round 4
// 322.613 us; speedup vs baseline: 3.5847x; 3.5847x over previous
//
#include <hip/hip_runtime.h>

#define N_NODES 100000
#define N_EDGES 1600000
#define EMBED_DIM 64

#define SCAN_BLK 256
#define SCAN_ITEMS 4
#define SCAN_CHUNK (SCAN_BLK * SCAN_ITEMS)                 // 1024
#define SCAN_NB ((N_NODES + SCAN_CHUNK - 1) / SCAN_CHUNK)  // 98

// ---------- pass 1: histogram of rows ----------
__global__ __launch_bounds__(256) void k_hist(const int* __restrict__ rows,
                                              int* __restrict__ cnt) {
    int e = blockIdx.x * 256 + threadIdx.x;
    if (e < N_EDGES) atomicAdd(&cnt[rows[e]], 1);
}

// ---------- pass 2a: per-block reduce of cnt ----------
__global__ __launch_bounds__(SCAN_BLK) void k_reduce(const int* __restrict__ cnt,
                                                     int* __restrict__ bsum) {
    __shared__ int s[SCAN_BLK];
    int tid = threadIdx.x;
    int base = blockIdx.x * SCAN_CHUNK + tid * SCAN_ITEMS;
    int t = 0;
#pragma unroll
    for (int i = 0; i < SCAN_ITEMS; ++i) {
        int idx = base + i;
        if (idx < N_NODES) t += cnt[idx];
    }
    s[tid] = t;
    __syncthreads();
    for (int off = SCAN_BLK / 2; off > 0; off >>= 1) {
        if (tid < off) s[tid] += s[tid + off];
        __syncthreads();
    }
    if (tid == 0) bsum[blockIdx.x] = s[0];
}

// ---------- pass 2b: exclusive scan of block sums (single block) ----------
__global__ __launch_bounds__(128) void k_scan_bsum(int* __restrict__ bsum,
                                                   int* __restrict__ row_ptr) {
    __shared__ int s[128];
    int tid = threadIdx.x;
    s[tid] = (tid < SCAN_NB) ? bsum[tid] : 0;
    __syncthreads();
    for (int off = 1; off < 128; off <<= 1) {
        int v = s[tid];
        int add = (tid >= off) ? s[tid - off] : 0;
        __syncthreads();
        s[tid] = v + add;
        __syncthreads();
    }
    if (tid < SCAN_NB) bsum[tid] = (tid == 0) ? 0 : s[tid - 1];
    if (tid == 0) row_ptr[N_NODES] = N_EDGES;
}

// ---------- pass 2c: final scan -> row_ptr + cursor ----------
__global__ __launch_bounds__(SCAN_BLK) void k_scan_final(const int* __restrict__ cnt,
                                                         const int* __restrict__ bsum,
                                                         int* __restrict__ row_ptr,
                                                         int* __restrict__ cursor) {
    __shared__ int s[SCAN_BLK];
    int tid = threadIdx.x;
    int base = blockIdx.x * SCAN_CHUNK + tid * SCAN_ITEMS;
    int v[SCAN_ITEMS];
    int t = 0;
#pragma unroll
    for (int i = 0; i < SCAN_ITEMS; ++i) {
        int idx = base + i;
        v[i] = (idx < N_NODES) ? cnt[idx] : 0;
        t += v[i];
    }
    s[tid] = t;
    __syncthreads();
    for (int off = 1; off < SCAN_BLK; off <<= 1) {
        int a = s[tid];
        int add = (tid >= off) ? s[tid - off] : 0;
        __syncthreads();
        s[tid] = a + add;
        __syncthreads();
    }
    int run = ((tid == 0) ? 0 : s[tid - 1]) + bsum[blockIdx.x];
#pragma unroll
    for (int i = 0; i < SCAN_ITEMS; ++i) {
        int idx = base + i;
        if (idx < N_NODES) {
            row_ptr[idx] = run;
            cursor[idx] = run;
        }
        run += v[i];
    }
}

// ---------- pass 3: scatter packed (col,val) int2 into CSR order ----------
__global__ __launch_bounds__(256) void k_scatter(const int* __restrict__ rows,
                                                 const int* __restrict__ cols,
                                                 const float* __restrict__ vals,
                                                 int* __restrict__ cursor,
                                                 int2* __restrict__ packed) {
    int e = blockIdx.x * 256 + threadIdx.x;
    if (e >= N_EDGES) return;
    int r = rows[e];
    int p = atomicAdd(&cursor[r], 1);
    packed[p] = make_int2(cols[e], __float_as_int(vals[e]));
}

// ---------- pass 4: one wave per row; cooperative edge-list load + readlane ----------
// Row's edges are contiguous: lanes cooperatively load up to 32 (col,val) pairs
// (4B/lane coalesced), then readlane-broadcast each pair. col lands in an SGPR
// -> saddr-form X loads; 16 gather loads issue back-to-back per chunk.
// Lanes past 2*win hold w=0 -> v=0, c=0: contributes 0 via a cheap L1-hit load.
__global__ __launch_bounds__(256) void k_gather(const float* __restrict__ x,
                                                const int* __restrict__ row_ptr,
                                                const int* __restrict__ pw,  // packed as ints
                                                float* __restrict__ out) {
    int wid = (blockIdx.x * 256 + threadIdx.x) >> 6;  // row id
    int lane = threadIdx.x & 63;                      // dim id
    if (wid >= N_NODES) return;
    int beg = row_ptr[wid];
    int end = row_ptr[wid + 1];
    int deg = end - beg;
    float acc = 0.f;
    int done = 0;
    while (done < deg) {
        int win = deg - done;
        if (win > 32) win = 32;
        int w = 0;
        if (lane < 2 * win) w = pw[2 * (beg + done) + lane];
        for (int k0 = 0; k0 < win; k0 += 16) {
#pragma unroll
            for (int k = 0; k < 16; ++k) {
                int kk = k0 + k;
                int c = __builtin_amdgcn_readlane(w, 2 * kk);
                float v = __int_as_float(__builtin_amdgcn_readlane(w, 2 * kk + 1));
                acc += v * x[c * EMBED_DIM + lane];
            }
        }
        done += win;
    }
    out[wid * EMBED_DIM + lane] = acc;
}

// ---------- fallback (ws too small): atomic scatter ----------
__global__ __launch_bounds__(256) void spmm_scatter_kernel(
    const float* __restrict__ x, const float* __restrict__ vals,
    const int* __restrict__ rows, const int* __restrict__ cols,
    float* __restrict__ out) {
    const int wave_in_block = threadIdx.x >> 6;
    const int lane = threadIdx.x & 63;
    const int e = blockIdx.x * 4 + wave_in_block;
    if (e >= N_EDGES) return;
    const float m = vals[e] * x[cols[e] * EMBED_DIM + lane];
    atomicAdd(&out[rows[e] * EMBED_DIM + lane], m);
}

extern "C" void kernel_launch(void* const* d_in, const int* in_sizes, int n_in,
                              void* d_out, int out_size, void* d_ws, size_t ws_size,
                              hipStream_t stream) {
    const float* x    = (const float*)d_in[0];
    const float* vals = (const float*)d_in[1];
    const int*   rows = (const int*)d_in[2];
    const int*   cols = (const int*)d_in[3];
    float* out = (float*)d_out;

    // Workspace: packed int2[E] FIRST (8B-aligned at offset 0), then
    // row_ptr N+1 | cnt N | cursor N | bsum 128 (ints)
    const size_t need = 2ull * N_EDGES * 4 + ((size_t)(3 * N_NODES + 1 + 128)) * 4;
    if (ws_size < need) {
        hipMemsetAsync(out, 0, (size_t)out_size * sizeof(float), stream);
        spmm_scatter_kernel<<<(N_EDGES + 3) / 4, 256, 0, stream>>>(x, vals, rows, cols, out);
        return;
    }

    int2* packed = (int2*)d_ws;
    int* row_ptr = (int*)d_ws + 2ull * N_EDGES;
    int* cnt     = row_ptr + (N_NODES + 1);
    int* cursor  = cnt + N_NODES;
    int* bsum    = cursor + N_NODES;

    hipMemsetAsync(cnt, 0, (size_t)N_NODES * sizeof(int), stream);

    k_hist<<<(N_EDGES + 255) / 256, 256, 0, stream>>>(rows, cnt);
    k_reduce<<<SCAN_NB, SCAN_BLK, 0, stream>>>(cnt, bsum);
    k_scan_bsum<<<1, 128, 0, stream>>>(bsum, row_ptr);
    k_scan_final<<<SCAN_NB, SCAN_BLK, 0, stream>>>(cnt, bsum, row_ptr, cursor);
    k_scatter<<<(N_EDGES + 255) / 256, 256, 0, stream>>>(rows, cols, vals, cursor, packed);
    k_gather<<<(N_NODES * 64 + 255) / 256, 256, 0, stream>>>(x, row_ptr, (const int*)packed, out);
}

// Round 5
// 186.720 us; speedup vs baseline: 6.1936x; 1.7278x over previous
//
#include <hip/hip_runtime.h>

#define N_NODES 100000
#define N_EDGES 1600000
#define EMBED_DIM 64

#define RPB 256                                   // rows per bucket
#define NBKT ((N_NODES + RPB - 1) / RPB)          // 391
#define CAP 4608                                  // slots per bucket (mean 4092, +8 sigma)
#define TILE 4096                                 // edges per binA block
#define NTILE ((N_EDGES + TILE - 1) / TILE)       // 391
#define OVCAP 8192                                // overflow backstop

// ---------- pass A: tile counting-sort into bucket regions (dense writes) ----------
__global__ __launch_bounds__(256) void k_binA(const int* __restrict__ rows,
                                              const int* __restrict__ cols,
                                              const float* __restrict__ vals,
                                              int* __restrict__ gcur,
                                              int2* __restrict__ packed,
                                              int* __restrict__ ov_cnt,
                                              int4* __restrict__ ov) {
    __shared__ int hist[NBKT];
    __shared__ int off[NBKT];
    __shared__ int cur[NBKT];
    __shared__ int gbase[NBKT];
    __shared__ int ssum[256];
    __shared__ int2 stage[TILE];   // 32 KB
    __shared__ int dg[TILE];       // 16 KB
    const int tid = threadIdx.x;
    const int e0 = blockIdx.x * TILE;

    for (int i = tid; i < NBKT; i += 256) hist[i] = 0;
    __syncthreads();

    // pass 1: bucket histogram of this tile
    for (int i = tid; i < TILE; i += 256) {
        int e = e0 + i;
        if (e < N_EDGES) atomicAdd(&hist[rows[e] >> 8], 1);
    }
    __syncthreads();

    // exclusive scan over NBKT (2 items/thread, Hillis-Steele on partials)
    int b0 = 2 * tid, b1 = 2 * tid + 1;
    int h0 = (b0 < NBKT) ? hist[b0] : 0;
    int h1 = (b1 < NBKT) ? hist[b1] : 0;
    ssum[tid] = h0 + h1;
    __syncthreads();
    for (int o = 1; o < 256; o <<= 1) {
        int a = ssum[tid];
        int add = (tid >= o) ? ssum[tid - o] : 0;
        __syncthreads();
        ssum[tid] = a + add;
        __syncthreads();
    }
    int base = (tid == 0) ? 0 : ssum[tid - 1];
    if (b0 < NBKT) { off[b0] = base; cur[b0] = base; }
    if (b1 < NBKT) { off[b1] = base + h0; cur[b1] = base + h0; }

    // bulk global reservation: one atomic per non-empty bucket
    for (int b = tid; b < NBKT; b += 256) {
        int c = hist[b];
        gbase[b] = c ? atomicAdd(&gcur[b], c) : 0;
    }
    __syncthreads();

    // pass 2: place edges grouped-by-bucket into LDS staging
    for (int i = tid; i < TILE; i += 256) {
        int e = e0 + i;
        if (e < N_EDGES) {
            int r = rows[e];
            int b = r >> 8;
            int p = atomicAdd(&cur[b], 1);
            stage[p] = make_int2(((r & (RPB - 1)) << 17) | cols[e],
                                 __float_as_int(vals[e]));
            int d = gbase[b] + (p - off[b]);
            dg[p] = (d < CAP) ? (b * CAP + d) : (0x40000000 | b);
        }
    }
    __syncthreads();

    // flush: consecutive staged elements -> consecutive global slots (dense lines)
    int total = ssum[255];
    for (int j = tid; j < total; j += 256) {
        int d = dg[j];
        int2 ev = stage[j];
        if (d & 0x40000000) {  // overflow backstop (statistically never)
            int b = d & 0xFFFF;
            int ovi = atomicAdd(ov_cnt, 1);
            if (ovi < OVCAP) {
                int r = b * RPB + (((unsigned)ev.x) >> 17);
                ov[ovi] = make_int4(r, ev.x & 0x1FFFF, ev.y, 0);
            }
        } else {
            packed[d] = ev;
        }
    }
}

// ---------- pass B: per-bucket row-sort + row_ptr/cnt emission ----------
__global__ __launch_bounds__(256) void k_binB(const int* __restrict__ gcur,
                                              int2* __restrict__ packed,
                                              int* __restrict__ row_ptr,
                                              int* __restrict__ cnt) {
    __shared__ int2 stage[CAP];    // 36 KB
    __shared__ int h[RPB];
    __shared__ int s[RPB];
    __shared__ int cur[RPB];
    const int b = blockIdx.x;
    const int tid = threadIdx.x;
    int n = gcur[b];
    if (n > CAP) n = CAP;
    const int base = b * CAP;

    h[tid] = 0;
    __syncthreads();
    for (int j = tid; j < n; j += 256) {
        int2 e = packed[base + j];
        stage[j] = e;
        atomicAdd(&h[((unsigned)e.x) >> 17], 1);
    }
    __syncthreads();

    int hv = h[tid];
    s[tid] = hv;
    __syncthreads();
    for (int o = 1; o < 256; o <<= 1) {
        int a = s[tid];
        int add = (tid >= o) ? s[tid - o] : 0;
        __syncthreads();
        s[tid] = a + add;
        __syncthreads();
    }
    int ofs = (tid == 0) ? 0 : s[tid - 1];
    cur[tid] = ofs;
    int r = b * RPB + tid;
    if (r < N_NODES) {
        row_ptr[r] = base + ofs;
        cnt[r] = hv;
    }
    __syncthreads();

    // in-region row-sorted rewrite (source is LDS -> no RAW hazard)
    for (int j = tid; j < n; j += 256) {
        int2 e = stage[j];
        int lr = ((unsigned)e.x) >> 17;
        int p = atomicAdd(&cur[lr], 1);
        packed[base + p] = e;
    }
}

// ---------- gather: one wave per row; cooperative edge load + readlane ----------
__global__ __launch_bounds__(256) void k_gather(const float* __restrict__ x,
                                                const int* __restrict__ row_ptr,
                                                const int* __restrict__ cnt,
                                                const int* __restrict__ pw,
                                                float* __restrict__ out) {
    int wid = (blockIdx.x * 256 + threadIdx.x) >> 6;
    int lane = threadIdx.x & 63;
    if (wid >= N_NODES) return;
    int beg = row_ptr[wid];
    int deg = cnt[wid];
    float acc = 0.f;
    int done = 0;
    while (done < deg) {
        int win = deg - done;
        if (win > 32) win = 32;
        int w = 0;
        if (lane < 2 * win) w = pw[2 * (beg + done) + lane];
        for (int k0 = 0; k0 < win; k0 += 16) {
#pragma unroll
            for (int k = 0; k < 16; ++k) {
                int kk = k0 + k;
                int cpack = __builtin_amdgcn_readlane(w, 2 * kk);
                float v = __int_as_float(__builtin_amdgcn_readlane(w, 2 * kk + 1));
                acc += v * x[(cpack & 0x1FFFF) * EMBED_DIM + lane];
            }
        }
        done += win;
    }
    out[wid * EMBED_DIM + lane] = acc;
}

// ---------- overflow cleanup (runs after gather; expected n==0) ----------
__global__ __launch_bounds__(256) void k_overflow(const float* __restrict__ x,
                                                  const int* __restrict__ ov_cnt,
                                                  const int4* __restrict__ ov,
                                                  float* __restrict__ out) {
    int n = *ov_cnt;
    if (n > OVCAP) n = OVCAP;
    int idx = (blockIdx.x * 256 + threadIdx.x) >> 6;
    int lane = threadIdx.x & 63;
    if (idx >= n) return;
    int4 e = ov[idx];
    atomicAdd(&out[e.x * EMBED_DIM + lane],
              __int_as_float(e.z) * x[e.y * EMBED_DIM + lane]);
}

// ---------- fallback (ws too small): atomic scatter ----------
__global__ __launch_bounds__(256) void spmm_scatter_kernel(
    const float* __restrict__ x, const float* __restrict__ vals,
    const int* __restrict__ rows, const int* __restrict__ cols,
    float* __restrict__ out) {
    const int wave_in_block = threadIdx.x >> 6;
    const int lane = threadIdx.x & 63;
    const int e = blockIdx.x * 4 + wave_in_block;
    if (e >= N_EDGES) return;
    const float m = vals[e] * x[cols[e] * EMBED_DIM + lane];
    atomicAdd(&out[rows[e] * EMBED_DIM + lane], m);
}

extern "C" void kernel_launch(void* const* d_in, const int* in_sizes, int n_in,
                              void* d_out, int out_size, void* d_ws, size_t ws_size,
                              hipStream_t stream) {
    const float* x    = (const float*)d_in[0];
    const float* vals = (const float*)d_in[1];
    const int*   rows = (const int*)d_in[2];
    const int*   cols = (const int*)d_in[3];
    float* out = (float*)d_out;

    // ws layout: packed[NBKT*CAP] int2 | ov[OVCAP] int4 | gcur[NBKT] | row_ptr[N] | cnt[N] | ov_cnt
    const size_t packed_b = (size_t)NBKT * CAP * 8;         // 14,413,824 (16B-aligned)
    const size_t ov_b     = (size_t)OVCAP * 16;
    const size_t need = packed_b + ov_b + ((size_t)NBKT + 2 * N_NODES + 1) * 4;
    if (ws_size < need) {
        hipMemsetAsync(out, 0, (size_t)out_size * sizeof(float), stream);
        spmm_scatter_kernel<<<(N_EDGES + 3) / 4, 256, 0, stream>>>(x, vals, rows, cols, out);
        return;
    }

    int2* packed = (int2*)d_ws;
    int4* ov     = (int4*)((char*)d_ws + packed_b);
    int*  gcur   = (int*)((char*)d_ws + packed_b + ov_b);
    int*  row_ptr = gcur + NBKT;
    int*  cnt     = row_ptr + N_NODES;
    int*  ov_cnt  = cnt + N_NODES;

    // zero gcur + ov_cnt (adjacent-ish: zero gcur..ov_cnt span = NBKT+2N+1 ints ~0.8MB; cheaper: two memsets)
    hipMemsetAsync(gcur, 0, (size_t)NBKT * sizeof(int), stream);
    hipMemsetAsync(ov_cnt, 0, sizeof(int), stream);

    k_binA<<<NTILE, 256, 0, stream>>>(rows, cols, vals, gcur, packed, ov_cnt, ov);
    k_binB<<<NBKT, 256, 0, stream>>>(gcur, packed, row_ptr, cnt);
    k_gather<<<(N_NODES * 64 + 255) / 256, 256, 0, stream>>>(x, row_ptr, cnt, (const int*)packed, out);
    k_overflow<<<(OVCAP + 3) / 4, 256, 0, stream>>>(x, ov_cnt, ov, out);
}